// Round 8
// baseline (176.856 us; speedup 1.0000x reference)
//
#include <hip/hip_runtime.h>
#include <stdint.h>

#define N_Q   65536
#define N_S   65536
#define NB_H  26
#define PAD_H 28
#define KP    10
#define CIN   64
#define COUT  128
#define MT    16   // query points per fused block (512 threads)

typedef unsigned short u16x8  __attribute__((ext_vector_type(8)));
typedef float          f32x4  __attribute__((ext_vector_type(4)));
typedef float          f32x2  __attribute__((ext_vector_type(2)));
typedef _Float16       f16x8  __attribute__((ext_vector_type(8)));

static __device__ __forceinline__ unsigned short f2h(float f) {
  return __builtin_bit_cast(unsigned short, (_Float16)f);
}
// v_cvt_pkrtz_f16_f32 packed to raw u32 (builtin returns __fp16x2, not _Float16x2)
static __device__ __forceinline__ unsigned int pkrtz_u32(float a, float b) {
  return __builtin_bit_cast(unsigned int, __builtin_amdgcn_cvt_pkrtz(a, b));
}

// ---- prep: pack weights [640][128] fp32 -> MFMA B-fragment order fp16 -------
// Bpack[((ct*20 + ks)*64 + lane)*8 + j] = B[ks*32 + (lane>>4)*8 + j][ct*16 + (lane&15)]
__global__ void prep_kernel(const float* __restrict__ w,
                            unsigned short* __restrict__ bp) {
  int t = blockIdx.x * blockDim.x + threadIdx.x;
  if (t >= 8 * 20 * 64) return;
  int lane = t & 63;
  int frag = t >> 6;            // ct*20 + ks
  int ks = frag % 20;
  int ct = frag / 20;
  int row0 = ks * 32 + (lane >> 4) * 8;
  int col  = ct * 16 + (lane & 15);
  u16x8 o;
  #pragma unroll
  for (int j = 0; j < 8; ++j) o[j] = f2h(w[(row0 + j) * COUT + col]);
  *(u16x8*)(bp + (long)t * 8) = o;
}

// ---- fused kernel: phases A,A2,B(sparse-compact),C, D(MFMA) -> out ----------
// Sparsity fact (round 7, verified): w = max(1-d/1.2,0) is ~95% exactly zero;
// ~42% of neighbor rows touch any kernel point -> compact list, c ~ 11 of 26.
// LDS: ind 1664 + hoff 1664 + cnt 64 + pool 27008 = 30400 B.
// Pool overlay: {nbr 5120 | kp 1920 | sw 19968} all dead after phase-C MAC loop,
// then the same pool holds the MFMA A-fragment (16x648 fp16 = 20736 B).
__global__ void __launch_bounds__(512, 6)
kpconv_fused(const float* __restrict__ q_pts, const float* __restrict__ s_pts,
             const float* __restrict__ x, const float* __restrict__ gen_W,
             const float* __restrict__ gen_b, const int* __restrict__ inds,
             const unsigned short* __restrict__ bp, float* __restrict__ out) {

  __shared__ int          sh_ind[MT][NB_H];        // 1664 B
  __shared__ unsigned int sh_hoff[MT][NB_H];       // 1664 B  x element offset (ind*64)
  __shared__ int          sh_cnt[MT];              //   64 B
  __shared__ __align__(16) char pool[27008];

  float* sh_nbr = (float*)pool;                    // [MT][80]      5120 B
  float* sh_kp  = (float*)(pool + 5120);           // [MT][KP*3]    1920 B
  float* sh_w   = (float*)(pool + 7040);           // [MT][NB_H][12] 19968 B
  unsigned short* sh_frag = (unsigned short*)pool; // [MT][648]     20736 B (after C)

  const int tid  = threadIdx.x;
  const int base = blockIdx.x * MT;

  // ---- Phase A: neighbors = s_pad[ind] - q; init counters ----
  if (tid < MT) sh_cnt[tid] = 0;
  if (tid < MT * NB_H) {
    int m = tid / NB_H, h = tid % NB_H;
    int n = base + m;
    int ind = inds[n * NB_H + h];
    sh_ind[m][h] = ind;
    float sx, sy, sz;
    if ((unsigned)ind < (unsigned)N_S) {
      sx = s_pts[ind * 3 + 0]; sy = s_pts[ind * 3 + 1]; sz = s_pts[ind * 3 + 2];
    } else {
      sx = 1e6f; sy = 1e6f; sz = 1e6f;   // shadow support point
    }
    sh_nbr[m * 80 + h * 3 + 0] = sx - q_pts[n * 3 + 0];
    sh_nbr[m * 80 + h * 3 + 1] = sy - q_pts[n * 3 + 1];
    sh_nbr[m * 80 + h * 3 + 2] = sz - q_pts[n * 3 + 2];
  }
  if (tid < MT * 2) sh_nbr[(tid >> 1) * 80 + 78 + (tid & 1)] = -1.0f;
  __syncthreads();

  // ---- Phase A2: kp = padded @ gen_W^T + gen_b (float4-vectorized dot) ----
  // channels 0..77 = neighbors, 78..79 = -1 (in sh_nbr), 80..83 folded to bias.
  if (tid < MT * KP * 3) {
    int m = tid / 30, r = tid % 30;
    const float* Wr = gen_W + r * (PAD_H * 3);
    const f32x4* W4 = (const f32x4*)Wr;
    const f32x4* N4 = (const f32x4*)&sh_nbr[m * 80];
    f32x4 accv = {0.f, 0.f, 0.f, 0.f};
    #pragma unroll
    for (int j = 0; j < 20; ++j) accv += W4[j] * N4[j];
    sh_kp[m * 30 + r] = gen_b[r] - (Wr[80] + Wr[81] + Wr[82] + Wr[83])
                      + accv[0] + accv[1] + accv[2] + accv[3];
  }
  __syncthreads();

  // ---- Phase B: per (m,h) compute 10 w's; append row to compact list if any>0
  if (tid < MT * NB_H) {
    int m = tid / NB_H, h = tid % NB_H;
    float nx = sh_nbr[m * 80 + h * 3 + 0];
    float ny = sh_nbr[m * 80 + h * 3 + 1];
    float nz = sh_nbr[m * 80 + h * 3 + 2];
    float wv[KP];
    bool any = false;
    #pragma unroll
    for (int k = 0; k < KP; ++k) {
      float dx = nx - sh_kp[m * 30 + k * 3 + 0];
      float dy = ny - sh_kp[m * 30 + k * 3 + 1];
      float dz = nz - sh_kp[m * 30 + k * 3 + 2];
      float d  = sqrtf(dx * dx + dy * dy + dz * dz);
      float w  = fmaxf(1.0f - d * (1.0f / 1.2f), 0.0f);
      wv[k] = w;
      any = any || (w > 0.0f);
    }
    if (any) {
      int s = atomicAdd(&sh_cnt[m], 1);
      sh_hoff[m][s] = (unsigned int)sh_ind[m][h] * CIN;   // element offset into x (fp32)
      #pragma unroll
      for (int k = 0; k < KP; ++k) sh_w[m * 312 + s * 12 + k] = wv[k];
    }
  }
  __syncthreads();

  // ---- Phase C: weighted[m][k][i0..i0+1] over ACTIVE rows, x read as fp32 ----
  // 32 threads/point, 2 channels each; depth-4 statically-slotted prefetch.
  {
    const int m  = tid >> 5;
    const int i0 = (tid & 31) * 2;
    const int c  = sh_cnt[m];
    f32x2 acc[KP];
    #pragma unroll
    for (int k = 0; k < KP; ++k) acc[k] = (f32x2){0.f, 0.f};

    f32x2 xr0 = {0.f,0.f}, xr1 = {0.f,0.f}, xr2 = {0.f,0.f}, xr3 = {0.f,0.f};
    if (0 < c) xr0 = *(const f32x2*)(x + sh_hoff[m][0] + i0);
    if (1 < c) xr1 = *(const f32x2*)(x + sh_hoff[m][1] + i0);
    if (2 < c) xr2 = *(const f32x2*)(x + sh_hoff[m][2] + i0);
    if (3 < c) xr3 = *(const f32x2*)(x + sh_hoff[m][3] + i0);

    #define C_BODY(J, XR)                                                     \
      {                                                                       \
        f32x2 xp = XR;                                                        \
        if ((J) + 4 < c) XR = *(const f32x2*)(x + sh_hoff[m][(J) + 4] + i0);  \
        const float* wr = &sh_w[m * 312 + (J) * 12];                          \
        f32x4 wa = *(const f32x4*)&wr[0];                                     \
        f32x4 wb = *(const f32x4*)&wr[4];                                     \
        f32x2 wc = *(const f32x2*)&wr[8];                                     \
        acc[0] += (f32x2){wa[0], wa[0]} * xp;                                 \
        acc[1] += (f32x2){wa[1], wa[1]} * xp;                                 \
        acc[2] += (f32x2){wa[2], wa[2]} * xp;                                 \
        acc[3] += (f32x2){wa[3], wa[3]} * xp;                                 \
        acc[4] += (f32x2){wb[0], wb[0]} * xp;                                 \
        acc[5] += (f32x2){wb[1], wb[1]} * xp;                                 \
        acc[6] += (f32x2){wb[2], wb[2]} * xp;                                 \
        acc[7] += (f32x2){wb[3], wb[3]} * xp;                                 \
        acc[8] += (f32x2){wc[0], wc[0]} * xp;                                 \
        acc[9] += (f32x2){wc[1], wc[1]} * xp;                                 \
      }

    for (int j0 = 0; j0 < c; j0 += 4) {
      C_BODY(j0, xr0);
      if (j0 + 1 < c) C_BODY(j0 + 1, xr1);
      if (j0 + 2 < c) C_BODY(j0 + 2, xr2);
      if (j0 + 3 < c) C_BODY(j0 + 3, xr3);
    }
    #undef C_BODY

    __syncthreads();   // sw/nbr/kp fully consumed -> pool becomes the A-fragment
    #pragma unroll
    for (int k = 0; k < KP; ++k) {
      *(unsigned int*)&sh_frag[m * 648 + k * CIN + i0] = pkrtz_u32(acc[k][0], acc[k][1]);
    }
  }
  __syncthreads();

  // ---- Phase D: out[16][128] = frag[16][640] @ B[640][128] (fp16 MFMA) ----
  // 8 waves x 1 col-tile each; B from L2-resident pre-packed frags.
  {
    const int ct   = tid >> 6;        // wave id = col tile 0..7
    const int lane = tid & 63;
    const int arow = lane & 15;
    const int ak   = (lane >> 4) * 8;
    f32x4 acc = {0.f, 0.f, 0.f, 0.f};
    for (int ks = 0; ks < 20; ++ks) {
      u16x8 au = *(const u16x8*)&sh_frag[arow * 648 + ks * 32 + ak];
      u16x8 bu = *(const u16x8*)(bp + (long)((ct * 20 + ks) * 64 + lane) * 8);
      f16x8 a = __builtin_bit_cast(f16x8, au);
      f16x8 b = __builtin_bit_cast(f16x8, bu);
      acc = __builtin_amdgcn_mfma_f32_16x16x32_f16(a, b, acc, 0, 0, 0);
    }
    // C/D layout: col = lane&15, row = (lane>>4)*4 + reg  [measured m89/m91]
    const int col   = lane & 15;
    const int rbase = (lane >> 4) * 4;
    #pragma unroll
    for (int r = 0; r < 4; ++r) {
      __builtin_nontemporal_store(
          acc[r], &out[(long)(base + rbase + r) * COUT + ct * 16 + col]);
    }
  }
}

extern "C" void kernel_launch(void* const* d_in, const int* in_sizes, int n_in,
                              void* d_out, int out_size, void* d_ws, size_t ws_size,
                              hipStream_t stream) {
  const float* q_pts = (const float*)d_in[0];
  const float* s_pts = (const float*)d_in[1];
  const float* x     = (const float*)d_in[2];
  const float* gen_W = (const float*)d_in[3];
  const float* gen_b = (const float*)d_in[4];
  const float* wts   = (const float*)d_in[5];
  const int*   inds  = (const int*)d_in[6];
  float* out = (float*)d_out;

  unsigned short* bp = (unsigned short*)d_ws;   // 81920 fp16 = 160 KB packed B

  prep_kernel<<<40, 256, 0, stream>>>(wts, bp);
  kpconv_fused<<<N_Q / MT, 512, 0, stream>>>(q_pts, s_pts, x, gen_W, gen_b,
                                             inds, bp, out);
}